// Round 1
// baseline (127.249 us; speedup 1.0000x reference)
//
#include <hip/hip_runtime.h>

#define NP    44
#define B     400000
#define B4    (B / 4)        // 100000 float4 groups per particle
#define BLK   256
#define CPT   8              // float4 chunks per thread (8 loads in flight)
#define CHUNK (BLK * CPT)    // 2048 float4 per block

// clang ext-vector type so __builtin_nontemporal_* accepts it directly
typedef float f4 __attribute__((ext_vector_type(4)));

// The whole bias-free 1->4->8->4->1 ReLU MLP is positively homogeneous in its
// scalar input:  y(x) = gp*x for x>=0,  gn*x for x<0.  Collapse per particle.
__device__ __forceinline__ void collapse_weights(
    const float* __restrict__ p1, const float* __restrict__ p2,
    const float* __restrict__ p3, const float* __restrict__ p4,
    float& gp, float& gn)
{
    float w1p[4], w1n[4];
#pragma unroll
    for (int k = 0; k < 4; ++k) {
        float w = p1[k];
        w1p[k] = fmaxf(w, 0.0f);
        w1n[k] = fminf(w, 0.0f);
    }

    float d2p[8], d2n[8];
#pragma unroll
    for (int i = 0; i < 8; ++i) {
        float ap = 0.0f, an = 0.0f;
#pragma unroll
        for (int k = 0; k < 4; ++k) {
            float w = p2[i * 4 + k];
            ap = fmaf(w, w1p[k], ap);
            an = fmaf(w, w1n[k], an);
        }
        d2p[i] = fmaxf(ap, 0.0f);   // relu branch for x>=0
        d2n[i] = fminf(an, 0.0f);   // relu branch for x<0  (relu(x*c) = x*min(c,0))
    }

    float f3p[4], f3n[4];
#pragma unroll
    for (int j = 0; j < 4; ++j) {
        float ap = 0.0f, an = 0.0f;
#pragma unroll
        for (int i = 0; i < 8; ++i) {
            float w = p3[j * 8 + i];
            ap = fmaf(w, d2p[i], ap);
            an = fmaf(w, d2n[i], an);
        }
        f3p[j] = fmaxf(ap, 0.0f);
        f3n[j] = fminf(an, 0.0f);
    }

    gp = 0.0f; gn = 0.0f;
#pragma unroll
    for (int j = 0; j < 4; ++j) {
        gp = fmaf(p4[j], f3p[j], gp);
        gn = fmaf(p4[j], f3n[j], gn);
    }
}

__device__ __forceinline__ f4 apply_gain(f4 v, float gp, float gn)
{
    f4 r;
    r.x = v.x * (v.x >= 0.0f ? gp : gn);
    r.y = v.y * (v.y >= 0.0f ? gp : gn);
    r.z = v.z * (v.z >= 0.0f ? gp : gn);
    r.w = v.w * (v.w >= 0.0f ? gp : gn);
    return r;
}

__global__ __launch_bounds__(BLK) void collapsed_mlp_kernel(
    const float* __restrict__ X,    // (NP, 1, B)
    const float* __restrict__ W1,   // (NP, 4, 1)
    const float* __restrict__ W2,   // (NP, 8, 4)
    const float* __restrict__ W3,   // (NP, 4, 8)
    const float* __restrict__ W4,   // (NP, 1, 4)
    float* __restrict__ out)        // (NP, 1, B)
{
    const int l    = blockIdx.y;
    const int base = blockIdx.x * CHUNK + threadIdx.x;

    const f4* Xp = (const f4*)(X + (size_t)l * B);
    f4*       Op = (f4*)(out + (size_t)l * B);

    const bool full = (blockIdx.x + 1) * CHUNK <= B4;

    // Issue the streaming loads first so they overlap the (uniform) collapse math.
    f4 xv[CPT];
    if (full) {
#pragma unroll
        for (int c = 0; c < CPT; ++c) xv[c] = Xp[base + c * BLK];
    }

    // Per-particle collapse — all operands wave-uniform (s_loads), ~150 VALU ops,
    // runs while the X loads are in flight.
    float gp, gn;
    collapse_weights(W1 + l * 4, W2 + l * 32, W3 + l * 32, W4 + l * 4, gp, gn);

    if (full) {
#pragma unroll
        for (int c = 0; c < CPT; ++c) {
            // Non-temporal store: output is never re-read; keep it from
            // evicting the X read stream in L2/LLC.
            __builtin_nontemporal_store(apply_gain(xv[c], gp, gn),
                                        &Op[base + c * BLK]);
        }
    } else {
#pragma unroll
        for (int c = 0; c < CPT; ++c) {
            const int idx = base + c * BLK;
            if (idx < B4) {
                f4 v = Xp[idx];
                __builtin_nontemporal_store(apply_gain(v, gp, gn), &Op[idx]);
            }
        }
    }
}

extern "C" void kernel_launch(void* const* d_in, const int* in_sizes, int n_in,
                              void* d_out, int out_size, void* d_ws, size_t ws_size,
                              hipStream_t stream) {
    const float* X  = (const float*)d_in[0];
    const float* W1 = (const float*)d_in[1];
    const float* W2 = (const float*)d_in[2];
    const float* W3 = (const float*)d_in[3];
    const float* W4 = (const float*)d_in[4];
    float* out = (float*)d_out;

    // (49, 44) blocks: 2156 total ≈ one resident round (8 blocks/CU x 256 CU),
    // each block streams 2048 float4 in / 2048 float4 out.
    dim3 grid((B4 + CHUNK - 1) / CHUNK, NP);
    collapsed_mlp_kernel<<<grid, BLK, 0, stream>>>(X, W1, W2, W3, W4, out);
}